// Round 9
// baseline (115.209 us; speedup 1.0000x reference)
//
#include <hip/hip_runtime.h>

// Geometry (fixed): imgs [2,1,128,128,128] f32, flow [2,3,128,128,128] f32
#define VOL   4194304
#define FLOWN 12582912
#define SMCNT 12484608.0f   // 2*3*127*128*128
#define WIN_INV (1.0f / 729.0f)

__device__ __forceinline__ void block_reduce_atomic(float v, float* red, float* dst) {
#pragma unroll
    for (int off = 32; off; off >>= 1) v += __shfl_down(v, off);
    if ((threadIdx.x & 63) == 0) red[threadIdx.x >> 6] = v;
    __syncthreads();
    if (threadIdx.x == 0) atomicAdd(dst, red[0] + red[1] + red[2] + red[3]);
}

struct __align__(16) NccLds {
    float wst[2][5][16][28];  // [plane][chan][w][rr] W-sums transposed; rr 24->28 pad
    float hst[2][5][16][16];  // [plane][chan][w][h]  H-sums (16: final read is 2-way)
};
// 17920 + 10240 = 28160 B -> 5 blocks/CU

// sliding 9-window over 12 inputs -> 4 outputs, transposed write at row wrr
#define WSLIDE(c, X0,X1,X2,X3,X4,X5,X6,X7,X8,X9,X10,X11)                   \
    {                                                                      \
        const float o0 = X0+X1+X2+X3+X4+X5+X6+X7+X8;                       \
        const float o1 = o0 - X0 + X9;                                     \
        const float o2 = o1 - X1 + X10;                                    \
        const float o3 = o2 - X2 + X11;                                    \
        L->wst[wpl][c][wq4 + 0][wrr] = o0;                                 \
        L->wst[wpl][c][wq4 + 1][wrr] = o1;                                 \
        L->wst[wpl][c][wq4 + 2][wrr] = o2;                                 \
        L->wst[wpl][c][wq4 + 3][wrr] = o3;                                 \
    }

#define EMIT {                                                             \
        const float cross = S[4] - S[0] * S[1] * WIN_INV;                  \
        const float iv    = S[2] - S[0] * S[0] * WIN_INV;                  \
        const float jv    = S[3] - S[1] * S[1] * WIN_INV;                  \
        local += cross * cross / (iv * jv + 1e-5f);                       \
    }

// Block = (n, 16h x 16w tile, 32-deep d-chunk): 40 planes in 20 pairs.
// vs 16-deep: halo work/output 1.25x (was 1.5x), barriers/output 1.25 (was
// 1.5), and only 512 ncc blocks -> ALL concurrent (single generation, no
// sequential ncc tail). Pair loop fully unrolled so the 9-deep D-ring index
// (plane % 9) is a compile-time constant: no hist shuffling (was 35
// v_mov/pair/thread).
__device__ void ncc_block(const float* __restrict__ I, const float* __restrict__ J,
                          float* __restrict__ acc, NccLds* L, float* red, int nb) {
    const int wt = nb & 7, ht = (nb >> 3) & 7, dc = (nb >> 6) & 3, n = nb >> 8;
    const int w0 = wt << 4, h0 = ht << 4, d0 = dc << 5;
    const int tid = threadIdx.x;
    const int th = tid & 15;        // owned h
    const int tw = tid >> 4;        // owned w

    // W-phase decomposition: threads 0..191 -> (plane 0/1, rr 0..23, q 0..3)
    const int wpl = tid / 96;
    const int wit = tid - wpl * 96;
    const int wrr = wit >> 2;
    const int wq4 = (wit & 3) << 2;
    const int gh  = h0 - 4 + wrr;
    const int gwb = w0 + wq4 - 4;   // first of 3 aligned float4 columns
    const bool wthr = (tid < 192) && ((unsigned)gh < 128u);

    float hist[5][9];               // ring; all indices compile-time (full unroll)
#pragma unroll
    for (int c = 0; c < 5; ++c)
#pragma unroll
        for (int k = 0; k < 9; ++k) hist[c][k] = 0.f;
    float S[5] = {0.f, 0.f, 0.f, 0.f, 0.f};
    float local = 0.f;
    const long nbase = (long)n * 2097152;

#pragma unroll
    for (int pp = 0; pp < 20; ++pp) {
        // ---- W phase: global(L2) -> regs -> wst (transposed) ----
        {
            const int dp = d0 - 4 + 2 * pp + wpl;
            if (wthr && (unsigned)dp < 128u) {
                const float4 z4 = make_float4(0.f, 0.f, 0.f, 0.f);
                float4 i0 = z4, i1 = z4, i2 = z4, j0 = z4, j1 = z4, j2 = z4;
                const float* Ip = I + nbase + (long)dp * 16384 + gh * 128 + gwb;
                const float* Jp = J + nbase + (long)dp * 16384 + gh * 128 + gwb;
                if (gwb >= 0)   { i0 = *(const float4*)Ip;       j0 = *(const float4*)Jp; }
                i1 = *(const float4*)(Ip + 4);                   j1 = *(const float4*)(Jp + 4);
                if (gwb <= 116) { i2 = *(const float4*)(Ip + 8); j2 = *(const float4*)(Jp + 8); }
                WSLIDE(0, i0.x,i0.y,i0.z,i0.w, i1.x,i1.y,i1.z,i1.w, i2.x,i2.y,i2.z,i2.w)
                WSLIDE(1, j0.x,j0.y,j0.z,j0.w, j1.x,j1.y,j1.z,j1.w, j2.x,j2.y,j2.z,j2.w)
                WSLIDE(2, i0.x*i0.x,i0.y*i0.y,i0.z*i0.z,i0.w*i0.w,
                          i1.x*i1.x,i1.y*i1.y,i1.z*i1.z,i1.w*i1.w,
                          i2.x*i2.x,i2.y*i2.y,i2.z*i2.z,i2.w*i2.w)
                WSLIDE(3, j0.x*j0.x,j0.y*j0.y,j0.z*j0.z,j0.w*j0.w,
                          j1.x*j1.x,j1.y*j1.y,j1.z*j1.z,j1.w*j1.w,
                          j2.x*j2.x,j2.y*j2.y,j2.z*j2.z,j2.w*j2.w)
                WSLIDE(4, i0.x*j0.x,i0.y*j0.y,i0.z*j0.z,i0.w*j0.w,
                          i1.x*j1.x,i1.y*j1.y,i1.z*j1.z,i1.w*j1.w,
                          i2.x*j2.x,i2.y*j2.y,i2.z*j2.z,i2.w*j2.w)
            }
        }
        __syncthreads();
        // ---- H phase: 640 items = (plane, c, w, qh); sliding along rr ----
#pragma unroll
        for (int rep = 0; rep < 3; ++rep) {
            int id = -1;
            if (rep < 2) id = tid + rep * 256;
            else if (tid >= 128) id = 384 + tid;      // waves 2,3 take the tail
            if (id >= 0 && id < 640) {
                const int pl = id >= 320;
                const int r2 = id - pl * 320;
                const int c  = r2 >> 6;
                const int w  = (r2 >> 2) & 15;
                const int qh = r2 & 3;
                const int dp = d0 - 4 + 2 * pp + pl;
                if ((unsigned)dp < 128u) {
                    const float* sp = &L->wst[pl][c][w][qh << 2];
                    const float4 a0 = *(const float4*)sp;
                    const float4 a1 = *(const float4*)(sp + 4);
                    const float4 a2 = *(const float4*)(sp + 8);
                    const float o0 = a0.x+a0.y+a0.z+a0.w+a1.x+a1.y+a1.z+a1.w+a2.x;
                    const float o1 = o0 - a0.x + a2.y;
                    const float o2 = o1 - a0.y + a2.z;
                    const float o3 = o2 - a0.z + a2.w;
                    *(float4*)&L->hst[pl][c][w][qh << 2] = make_float4(o0, o1, o2, o3);
                }
            }
        }
        __syncthreads();
        // ---- final: D running window, static ring slots (pp is literal) ----
        {
            const int s0 = 2 * pp, s1 = 2 * pp + 1;
            const int k0 = s0 % 9, k1 = s1 % 9;     // compile-time
            const int dp0 = d0 - 4 + s0;
            float p0[5], p1[5];
            if ((unsigned)dp0 < 128u) {
#pragma unroll
                for (int c = 0; c < 5; ++c) p0[c] = L->hst[0][c][tw][th];
            } else {
#pragma unroll
                for (int c = 0; c < 5; ++c) p0[c] = 0.f;
            }
            if ((unsigned)(dp0 + 1) < 128u) {
#pragma unroll
                for (int c = 0; c < 5; ++c) p1[c] = L->hst[1][c][tw][th];
            } else {
#pragma unroll
                for (int c = 0; c < 5; ++c) p1[c] = 0.f;
            }
#pragma unroll
            for (int c = 0; c < 5; ++c) {
                S[c] += p0[c] - hist[c][k0];
                hist[c][k0] = p0[c];
            }
            if (s0 >= 8) EMIT
#pragma unroll
            for (int c = 0; c < 5; ++c) {
                S[c] += p1[c] - hist[c][k1];
                hist[c][k1] = p1[c];
            }
            if (s1 >= 8) EMIT
        }
    }
    block_reduce_atomic(local, red, &acc[0]);
}

__device__ void mse_block(const float4* __restrict__ a, const float4* __restrict__ b,
                          float* __restrict__ acc, float* red, int mb) {
    float local = 0.f;
    for (int i = mb * 256 + threadIdx.x; i < VOL / 4; i += 512 * 256) {
        const float4 x = a[i], y = b[i];
        const float d0 = x.x - y.x, d1 = x.y - y.y, d2 = x.z - y.z, d3 = x.w - y.w;
        local += d0 * d0 + d1 * d1 + d2 * d2 + d3 * d3;
    }
    block_reduce_atomic(local, red, &acc[1]);
}

__device__ void smooth_block(const float4* __restrict__ s,
                             float* __restrict__ acc, float* red, int sb) {
    float local = 0.f;
    for (int f = sb * 256 + threadIdx.x; f < FLOWN / 4; f += 2048 * 256) {
        const int w4 = f & 31, h = (f >> 5) & 127, d = (f >> 12) & 127;
        const float4 v = s[f];
        const float t1 = v.y - v.x, t2 = v.z - v.y, t3 = v.w - v.z;
        local += t1 * t1 + t2 * t2 + t3 * t3;
        if (w4 < 31) {
            const float nx = ((const float*)s)[4 * f + 4];
            const float t = nx - v.w;
            local += t * t;
        }
        if (h < 127) {
            const float4 nh = s[f + 32];
            const float u0 = nh.x - v.x, u1 = nh.y - v.y, u2 = nh.z - v.z, u3 = nh.w - v.w;
            local += u0 * u0 + u1 * u1 + u2 * u2 + u3 * u3;
        }
        if (d < 127) {
            const float4 nd = s[f + 4096];
            const float u0 = nd.x - v.x, u1 = nd.y - v.y, u2 = nd.z - v.z, u3 = nd.w - v.w;
            local += u0 * u0 + u1 * u1 + u2 * u2 + u3 * u3;
        }
    }
    block_reduce_atomic(local, red, &acc[2]);
}

// 3072 blocks: g%6==0 -> ncc (512, 32-deep), ==1 -> mse (512), else smooth
// (2048). ncc spread 1/6 keeps each CU's 2 ncc blocks resident from t=0 with
// streaming blocks draining HBM around them.
__global__ __launch_bounds__(256) void fused_k(const float* __restrict__ imgsA,
                                               const float* __restrict__ recon,
                                               const float* __restrict__ warped,
                                               const float* __restrict__ flow,
                                               float* __restrict__ acc) {
    __shared__ NccLds Lsh;
    __shared__ float red[4];
    const int g = blockIdx.x;
    const int r6 = g % 6, q6 = g / 6;
    if (r6 == 0)      ncc_block(warped, imgsA, acc, &Lsh, red, q6);
    else if (r6 == 1) mse_block((const float4*)imgsA, (const float4*)recon, acc, red, q6);
    else              smooth_block((const float4*)flow, acc, red, q6 * 4 + (r6 - 2));
}

__global__ void fin_k(const float* __restrict__ acc, float* __restrict__ out) {
    if (threadIdx.x == 0) {
        out[0] = 1.0f - acc[0] * (1.0f / (float)VOL);
        out[1] = acc[1] * (1.0f / (float)VOL);
        out[2] = acc[2] * (1.0f / (3.0f * SMCNT));
    }
}

extern "C" void kernel_launch(void* const* d_in, const int* in_sizes, int n_in,
                              void* d_out, int out_size, void* d_ws, size_t ws_size,
                              hipStream_t stream) {
    const float* imgsA  = (const float*)d_in[0];
    const float* recon  = (const float*)d_in[1];
    const float* warped = (const float*)d_in[2];
    const float* flow   = (const float*)d_in[3];
    float* out = (float*)d_out;
    float* acc = (float*)d_ws;

    hipMemsetAsync(d_ws, 0, 16, stream);
    fused_k<<<3072, 256, 0, stream>>>(imgsA, recon, warped, flow, acc);
    fin_k<<<1, 64, 0, stream>>>(acc, out);
}

// Round 10
// 82.047 us; speedup vs baseline: 1.4042x; 1.4042x over previous
//
#include <hip/hip_runtime.h>

// Geometry (fixed): imgs [2,1,128,128,128] f32, flow [2,3,128,128,128] f32
#define VOL   4194304
#define FLOWN 12582912
#define SMCNT 12484608.0f   // 2*3*127*128*128
#define WIN_INV (1.0f / 729.0f)

__device__ __forceinline__ void block_reduce_atomic(float v, float* red, float* dst) {
#pragma unroll
    for (int off = 32; off; off >>= 1) v += __shfl_down(v, off);
    if ((threadIdx.x & 63) == 0) red[threadIdx.x >> 6] = v;
    __syncthreads();
    if (threadIdx.x == 0) atomicAdd(dst, red[0] + red[1] + red[2] + red[3]);
}

struct __align__(16) NccLds {
    float wst[2][5][16][28];  // [plane][chan][w][rr] W-sums transposed; rr 24->28 pad
    float hst[2][5][16][16];  // [plane][chan][w][h]  H-sums (16: final read 2-way=free)
};
// 17920 + 10240 = 28160 B -> 5 blocks/CU (LDS-limited)

// sliding 9-window over 12 inputs -> 4 outputs, transposed write at row wrr
#define WSLIDE(c, X0,X1,X2,X3,X4,X5,X6,X7,X8,X9,X10,X11)                   \
    {                                                                      \
        const float o0 = X0+X1+X2+X3+X4+X5+X6+X7+X8;                       \
        const float o1 = o0 - X0 + X9;                                     \
        const float o2 = o1 - X1 + X10;                                    \
        const float o3 = o2 - X2 + X11;                                    \
        L->wst[wpl][c][wq4 + 0][wrr] = o0;                                 \
        L->wst[wpl][c][wq4 + 1][wrr] = o1;                                 \
        L->wst[wpl][c][wq4 + 2][wrr] = o2;                                 \
        L->wst[wpl][c][wq4 + 3][wrr] = o3;                                 \
    }

#define EMIT {                                                             \
        const float cross = S[4] - S[0] * S[1] * WIN_INV;                  \
        const float iv    = S[2] - S[0] * S[0] * WIN_INV;                  \
        const float jv    = S[3] - S[1] * S[1] * WIN_INV;                  \
        local += cross * cross / (iv * jv + 1e-5f);                       \
    }

// Block = (n, 16h x 16w tile, 16-deep d-chunk); 24 planes in 12 pairs,
// 2 barriers per pair. Next pair's 6 float4 loads are register-prefetched
// right after the current W phase consumes the regs, so L2/HBM latency hides
// under H + final + 2 barriers. (R8 retry WITHOUT launch_bounds min -> no
// spill, and WITHOUT the hst[20] pad -> final read stays 2-way-free.)
__device__ void ncc_block(const float* __restrict__ I, const float* __restrict__ J,
                          float* __restrict__ acc, NccLds* L, float* red, int nb) {
    const int wt = nb & 7, ht = (nb >> 3) & 7, dc = (nb >> 6) & 7, n = nb >> 9;
    const int w0 = wt << 4, h0 = ht << 4, d0 = dc << 4;
    const int tid = threadIdx.x;
    const int th = tid & 15;        // owned h
    const int tw = tid >> 4;        // owned w

    // W-phase decomposition: threads 0..191 -> (plane 0/1, rr 0..23, q 0..3)
    const int wpl = tid / 96;
    const int wit = tid - wpl * 96;
    const int wrr = wit >> 2;
    const int wq4 = (wit & 3) << 2;
    const int gh  = h0 - 4 + wrr;
    const int gwb = w0 + wq4 - 4;   // first of 3 aligned float4 columns
    const bool wthr = (tid < 192) && ((unsigned)gh < 128u);

    float hist[5][9];
#pragma unroll
    for (int c = 0; c < 5; ++c)
#pragma unroll
        for (int k = 0; k < 9; ++k) hist[c][k] = 0.f;
    float S[5] = {0.f, 0.f, 0.f, 0.f, 0.f};
    float local = 0.f;
    const long nbase = (long)n * 2097152;

    float4 Pi0, Pi1, Pi2, Pj0, Pj1, Pj2;   // prefetched regs for pair pp

    auto issue_loads = [&](int pp) {
        const int dp = d0 - 4 + 2 * pp + wpl;
        const float4 z4 = make_float4(0.f, 0.f, 0.f, 0.f);
        Pi0 = Pi1 = Pi2 = Pj0 = Pj1 = Pj2 = z4;
        if (wthr && (unsigned)dp < 128u) {
            const float* Ip = I + nbase + (long)dp * 16384 + gh * 128 + gwb;
            const float* Jp = J + nbase + (long)dp * 16384 + gh * 128 + gwb;
            if (gwb >= 0)   { Pi0 = *(const float4*)Ip;       Pj0 = *(const float4*)Jp; }
            Pi1 = *(const float4*)(Ip + 4);                   Pj1 = *(const float4*)(Jp + 4);
            if (gwb <= 116) { Pi2 = *(const float4*)(Ip + 8); Pj2 = *(const float4*)(Jp + 8); }
        }
    };

    issue_loads(0);
    for (int pp = 0; pp < 12; ++pp) {
        // ---- W phase: prefetched regs -> wst (transposed) ----
        {
            const int dp = d0 - 4 + 2 * pp + wpl;
            if (tid < 192 && (unsigned)dp < 128u) {
                const float4 i0 = Pi0, i1 = Pi1, i2 = Pi2;
                const float4 j0 = Pj0, j1 = Pj1, j2 = Pj2;
                WSLIDE(0, i0.x,i0.y,i0.z,i0.w, i1.x,i1.y,i1.z,i1.w, i2.x,i2.y,i2.z,i2.w)
                WSLIDE(1, j0.x,j0.y,j0.z,j0.w, j1.x,j1.y,j1.z,j1.w, j2.x,j2.y,j2.z,j2.w)
                WSLIDE(2, i0.x*i0.x,i0.y*i0.y,i0.z*i0.z,i0.w*i0.w,
                          i1.x*i1.x,i1.y*i1.y,i1.z*i1.z,i1.w*i1.w,
                          i2.x*i2.x,i2.y*i2.y,i2.z*i2.z,i2.w*i2.w)
                WSLIDE(3, j0.x*j0.x,j0.y*j0.y,j0.z*j0.z,j0.w*j0.w,
                          j1.x*j1.x,j1.y*j1.y,j1.z*j1.z,j1.w*j1.w,
                          j2.x*j2.x,j2.y*j2.y,j2.z*j2.z,j2.w*j2.w)
                WSLIDE(4, i0.x*j0.x,i0.y*j0.y,i0.z*j0.z,i0.w*j0.w,
                          i1.x*j1.x,i1.y*j1.y,i1.z*j1.z,i1.w*j1.w,
                          i2.x*j2.x,i2.y*j2.y,i2.z*j2.z,i2.w*j2.w)
            }
        }
        // issue next pair's loads now; they complete during H + final + barriers
        if (pp < 11) issue_loads(pp + 1);
        __syncthreads();
        // ---- H phase: 640 items = (plane, c, w, qh); sliding along rr ----
#pragma unroll
        for (int rep = 0; rep < 3; ++rep) {
            int id = -1;
            if (rep < 2) id = tid + rep * 256;
            else if (tid >= 128) id = 384 + tid;      // waves 2,3 take the tail
            if (id >= 0 && id < 640) {
                const int pl = id >= 320;
                const int r2 = id - pl * 320;
                const int c  = r2 >> 6;
                const int w  = (r2 >> 2) & 15;
                const int qh = r2 & 3;
                const int dp = d0 - 4 + 2 * pp + pl;
                if ((unsigned)dp < 128u) {
                    const float* sp = &L->wst[pl][c][w][qh << 2];
                    const float4 a0 = *(const float4*)sp;
                    const float4 a1 = *(const float4*)(sp + 4);
                    const float4 a2 = *(const float4*)(sp + 8);
                    const float o0 = a0.x+a0.y+a0.z+a0.w+a1.x+a1.y+a1.z+a1.w+a2.x;
                    const float o1 = o0 - a0.x + a2.y;
                    const float o2 = o1 - a0.y + a2.z;
                    const float o3 = o2 - a0.z + a2.w;
                    *(float4*)&L->hst[pl][c][w][qh << 2] = make_float4(o0, o1, o2, o3);
                }
            }
        }
        __syncthreads();
        // ---- final: D running window for both planes (static hist indices) ----
        {
            const int dp0 = d0 - 4 + 2 * pp;
            float p0[5], p1[5];
            if ((unsigned)dp0 < 128u) {
#pragma unroll
                for (int c = 0; c < 5; ++c) p0[c] = L->hst[0][c][tw][th];
            } else {
#pragma unroll
                for (int c = 0; c < 5; ++c) p0[c] = 0.f;
            }
            if ((unsigned)(dp0 + 1) < 128u) {
#pragma unroll
                for (int c = 0; c < 5; ++c) p1[c] = L->hst[1][c][tw][th];
            } else {
#pragma unroll
                for (int c = 0; c < 5; ++c) p1[c] = 0.f;
            }
#pragma unroll
            for (int c = 0; c < 5; ++c) S[c] += p0[c] - hist[c][8];
            if (pp >= 4) EMIT
#pragma unroll
            for (int c = 0; c < 5; ++c) S[c] += p1[c] - hist[c][7];
            if (pp >= 4) EMIT
#pragma unroll
            for (int c = 0; c < 5; ++c) {
                hist[c][8] = hist[c][6]; hist[c][7] = hist[c][5];
                hist[c][6] = hist[c][4]; hist[c][5] = hist[c][3];
                hist[c][4] = hist[c][2]; hist[c][3] = hist[c][1];
                hist[c][2] = hist[c][0];
                hist[c][1] = p0[c];
                hist[c][0] = p1[c];
            }
        }
    }
    block_reduce_atomic(local, red, &acc[0]);
}

__device__ void mse_block(const float4* __restrict__ a, const float4* __restrict__ b,
                          float* __restrict__ acc, float* red, int mb) {
    float local = 0.f;
    for (int i = mb * 256 + threadIdx.x; i < VOL / 4; i += 512 * 256) {
        const float4 x = a[i], y = b[i];
        const float d0 = x.x - y.x, d1 = x.y - y.y, d2 = x.z - y.z, d3 = x.w - y.w;
        local += d0 * d0 + d1 * d1 + d2 * d2 + d3 * d3;
    }
    block_reduce_atomic(local, red, &acc[1]);
}

__device__ void smooth_block(const float4* __restrict__ s,
                             float* __restrict__ acc, float* red, int sb) {
    float local = 0.f;
    for (int f = sb * 256 + threadIdx.x; f < FLOWN / 4; f += 2048 * 256) {
        const int w4 = f & 31, h = (f >> 5) & 127, d = (f >> 12) & 127;
        const float4 v = s[f];
        const float t1 = v.y - v.x, t2 = v.z - v.y, t3 = v.w - v.z;
        local += t1 * t1 + t2 * t2 + t3 * t3;
        if (w4 < 31) {
            const float nx = ((const float*)s)[4 * f + 4];
            const float t = nx - v.w;
            local += t * t;
        }
        if (h < 127) {
            const float4 nh = s[f + 32];
            const float u0 = nh.x - v.x, u1 = nh.y - v.y, u2 = nh.z - v.z, u3 = nh.w - v.w;
            local += u0 * u0 + u1 * u1 + u2 * u2 + u3 * u3;
        }
        if (d < 127) {
            const float4 nd = s[f + 4096];
            const float u0 = nd.x - v.x, u1 = nd.y - v.y, u2 = nd.z - v.z, u3 = nd.w - v.w;
            local += u0 * u0 + u1 * u1 + u2 * u2 + u3 * u3;
        }
    }
    block_reduce_atomic(local, red, &acc[2]);
}

// ncc blocks FIRST (g<1024) so every CU gets its long-pole blocks at t=0;
// mse (512) / smooth (2048) backfill and drain HBM concurrently.
__global__ __launch_bounds__(256) void fused_k(const float* __restrict__ imgsA,
                                               const float* __restrict__ recon,
                                               const float* __restrict__ warped,
                                               const float* __restrict__ flow,
                                               float* __restrict__ acc) {
    __shared__ NccLds Lsh;
    __shared__ float red[4];
    const int g = blockIdx.x;
    if (g < 1024) {
        ncc_block(warped, imgsA, acc, &Lsh, red, g);
    } else {
        const int x = g - 1024;
        const int q = x / 5, r = x - q * 5;
        if (r == 0) mse_block((const float4*)imgsA, (const float4*)recon, acc, red, q);
        else        smooth_block((const float4*)flow, acc, red, q * 4 + (r - 1));
    }
}

__global__ void fin_k(const float* __restrict__ acc, float* __restrict__ out) {
    if (threadIdx.x == 0) {
        out[0] = 1.0f - acc[0] * (1.0f / (float)VOL);
        out[1] = acc[1] * (1.0f / (float)VOL);
        out[2] = acc[2] * (1.0f / (3.0f * SMCNT));
    }
}

extern "C" void kernel_launch(void* const* d_in, const int* in_sizes, int n_in,
                              void* d_out, int out_size, void* d_ws, size_t ws_size,
                              hipStream_t stream) {
    const float* imgsA  = (const float*)d_in[0];
    const float* recon  = (const float*)d_in[1];
    const float* warped = (const float*)d_in[2];
    const float* flow   = (const float*)d_in[3];
    float* out = (float*)d_out;
    float* acc = (float*)d_ws;

    hipMemsetAsync(d_ws, 0, 16, stream);
    fused_k<<<3584, 256, 0, stream>>>(imgsA, recon, warped, flow, acc);
    fin_k<<<1, 64, 0, stream>>>(acc, out);
}

// Round 11
// 68.160 us; speedup vs baseline: 1.6903x; 1.2037x over previous
//
#include <hip/hip_runtime.h>

// Geometry (fixed): imgs [2,1,128,128,128] f32, flow [2,3,128,128,128] f32
#define VOL   4194304
#define FLOWN 12582912
#define SMCNT 12484608.0f   // 2*3*127*128*128
#define WIN_INV (1.0f / 729.0f)

__device__ __forceinline__ void block_reduce_atomic(float v, float* red, float* dst) {
#pragma unroll
    for (int off = 32; off; off >>= 1) v += __shfl_down(v, off);
    if ((threadIdx.x & 63) == 0) red[threadIdx.x >> 6] = v;
    __syncthreads();
    if (threadIdx.x == 0) atomicAdd(dst, red[0] + red[1] + red[2] + red[3]);
}

struct __align__(16) NccLds {
    float wst[2][5][16][25];  // [plane][chan][w][rr]; rr 24->25 (+1 pad).
                              // 25: W b32-writes 4-way (cheap), H b128 reads ~2-way.
                              // 28 gave 2-way writes but 28.2KB -> 5 slots/CU;
                              // 25 -> 26.24KB -> 6 slots/CU (the point: streaming
                              // blocks share this LDS size; more co-resident
                              // streaming blocks = HBM actually saturates).
    float hst[2][5][16][16];  // [plane][chan][w][h]; final read 2-way = free
};
// 16000 + 10240 = 26240 B -> 6 blocks/CU

// sliding 9-window over 12 inputs -> 4 outputs, transposed write at row wrr
#define WSLIDE(c, X0,X1,X2,X3,X4,X5,X6,X7,X8,X9,X10,X11)                   \
    {                                                                      \
        const float o0 = X0+X1+X2+X3+X4+X5+X6+X7+X8;                       \
        const float o1 = o0 - X0 + X9;                                     \
        const float o2 = o1 - X1 + X10;                                    \
        const float o3 = o2 - X2 + X11;                                    \
        L->wst[wpl][c][wq4 + 0][wrr] = o0;                                 \
        L->wst[wpl][c][wq4 + 1][wrr] = o1;                                 \
        L->wst[wpl][c][wq4 + 2][wrr] = o2;                                 \
        L->wst[wpl][c][wq4 + 3][wrr] = o3;                                 \
    }

#define EMIT {                                                             \
        const float cross = S[4] - S[0] * S[1] * WIN_INV;                  \
        const float iv    = S[2] - S[0] * S[0] * WIN_INV;                  \
        const float jv    = S[3] - S[1] * S[1] * WIN_INV;                  \
        local += cross * cross / (iv * jv + 1e-5f);                       \
    }

// Block = (n, 16h x 16w tile, 32-deep d-chunk): 40 planes in 20 pairs, ROLLED
// loop (R9 showed full unroll destroys I-cache). 512 blocks -> 2/CU, leaving
// 4 slots/CU for streaming blocks. Halo work 1.25x/output (was 1.5x at d16).
// Next pair's 6 float4 loads register-prefetched right after W consumes.
__device__ void ncc_block(const float* __restrict__ I, const float* __restrict__ J,
                          float* __restrict__ acc, NccLds* L, float* red, int nb) {
    const int wt = nb & 7, ht = (nb >> 3) & 7, dc = (nb >> 6) & 3, n = nb >> 8;
    const int w0 = wt << 4, h0 = ht << 4, d0 = dc << 5;
    const int tid = threadIdx.x;
    const int th = tid & 15;        // owned h
    const int tw = tid >> 4;        // owned w

    // W-phase decomposition: threads 0..191 -> (plane 0/1, rr 0..23, q 0..3)
    const int wpl = tid / 96;
    const int wit = tid - wpl * 96;
    const int wrr = wit >> 2;
    const int wq4 = (wit & 3) << 2;
    const int gh  = h0 - 4 + wrr;
    const int gwb = w0 + wq4 - 4;   // first of 3 aligned float4 columns
    const bool wthr = (tid < 192) && ((unsigned)gh < 128u);

    float hist[5][9];
#pragma unroll
    for (int c = 0; c < 5; ++c)
#pragma unroll
        for (int k = 0; k < 9; ++k) hist[c][k] = 0.f;
    float S[5] = {0.f, 0.f, 0.f, 0.f, 0.f};
    float local = 0.f;
    const long nbase = (long)n * 2097152;

    float4 Pi0, Pi1, Pi2, Pj0, Pj1, Pj2;   // prefetched regs for pair pp

    auto issue_loads = [&](int pp) {
        const int dp = d0 - 4 + 2 * pp + wpl;
        const float4 z4 = make_float4(0.f, 0.f, 0.f, 0.f);
        Pi0 = Pi1 = Pi2 = Pj0 = Pj1 = Pj2 = z4;
        if (wthr && (unsigned)dp < 128u) {
            const float* Ip = I + nbase + (long)dp * 16384 + gh * 128 + gwb;
            const float* Jp = J + nbase + (long)dp * 16384 + gh * 128 + gwb;
            if (gwb >= 0)   { Pi0 = *(const float4*)Ip;       Pj0 = *(const float4*)Jp; }
            Pi1 = *(const float4*)(Ip + 4);                   Pj1 = *(const float4*)(Jp + 4);
            if (gwb <= 116) { Pi2 = *(const float4*)(Ip + 8); Pj2 = *(const float4*)(Jp + 8); }
        }
    };

    issue_loads(0);
#pragma unroll 1
    for (int pp = 0; pp < 20; ++pp) {
        // ---- W phase: prefetched regs -> wst (transposed) ----
        {
            const int dp = d0 - 4 + 2 * pp + wpl;
            if (tid < 192 && (unsigned)dp < 128u) {
                const float4 i0 = Pi0, i1 = Pi1, i2 = Pi2;
                const float4 j0 = Pj0, j1 = Pj1, j2 = Pj2;
                WSLIDE(0, i0.x,i0.y,i0.z,i0.w, i1.x,i1.y,i1.z,i1.w, i2.x,i2.y,i2.z,i2.w)
                WSLIDE(1, j0.x,j0.y,j0.z,j0.w, j1.x,j1.y,j1.z,j1.w, j2.x,j2.y,j2.z,j2.w)
                WSLIDE(2, i0.x*i0.x,i0.y*i0.y,i0.z*i0.z,i0.w*i0.w,
                          i1.x*i1.x,i1.y*i1.y,i1.z*i1.z,i1.w*i1.w,
                          i2.x*i2.x,i2.y*i2.y,i2.z*i2.z,i2.w*i2.w)
                WSLIDE(3, j0.x*j0.x,j0.y*j0.y,j0.z*j0.z,j0.w*j0.w,
                          j1.x*j1.x,j1.y*j1.y,j1.z*j1.z,j1.w*j1.w,
                          j2.x*j2.x,j2.y*j2.y,j2.z*j2.z,j2.w*j2.w)
                WSLIDE(4, i0.x*j0.x,i0.y*j0.y,i0.z*j0.z,i0.w*j0.w,
                          i1.x*j1.x,i1.y*j1.y,i1.z*j1.z,i1.w*j1.w,
                          i2.x*j2.x,i2.y*j2.y,i2.z*j2.z,i2.w*j2.w)
            }
        }
        // issue next pair's loads now; they complete during H + final + barriers
        if (pp < 19) issue_loads(pp + 1);
        __syncthreads();
        // ---- H phase: 640 items = (plane, c, w, qh); sliding along rr ----
#pragma unroll
        for (int rep = 0; rep < 3; ++rep) {
            int id = -1;
            if (rep < 2) id = tid + rep * 256;
            else if (tid >= 128) id = 384 + tid;      // waves 2,3 take the tail
            if (id >= 0 && id < 640) {
                const int pl = id >= 320;
                const int r2 = id - pl * 320;
                const int c  = r2 >> 6;
                const int w  = (r2 >> 2) & 15;
                const int qh = r2 & 3;
                const int dp = d0 - 4 + 2 * pp + pl;
                if ((unsigned)dp < 128u) {
                    const float* sp = &L->wst[pl][c][w][qh << 2];
                    const float4 a0 = *(const float4*)sp;
                    const float4 a1 = *(const float4*)(sp + 4);
                    const float4 a2 = *(const float4*)(sp + 8);
                    const float o0 = a0.x+a0.y+a0.z+a0.w+a1.x+a1.y+a1.z+a1.w+a2.x;
                    const float o1 = o0 - a0.x + a2.y;
                    const float o2 = o1 - a0.y + a2.z;
                    const float o3 = o2 - a0.z + a2.w;
                    *(float4*)&L->hst[pl][c][w][qh << 2] = make_float4(o0, o1, o2, o3);
                }
            }
        }
        __syncthreads();
        // ---- final: D running window for both planes (shift ring, R5 style) ----
        {
            const int dp0 = d0 - 4 + 2 * pp;
            float p0[5], p1[5];
            if ((unsigned)dp0 < 128u) {
#pragma unroll
                for (int c = 0; c < 5; ++c) p0[c] = L->hst[0][c][tw][th];
            } else {
#pragma unroll
                for (int c = 0; c < 5; ++c) p0[c] = 0.f;
            }
            if ((unsigned)(dp0 + 1) < 128u) {
#pragma unroll
                for (int c = 0; c < 5; ++c) p1[c] = L->hst[1][c][tw][th];
            } else {
#pragma unroll
                for (int c = 0; c < 5; ++c) p1[c] = 0.f;
            }
#pragma unroll
            for (int c = 0; c < 5; ++c) S[c] += p0[c] - hist[c][8];
            if (pp >= 4) EMIT
#pragma unroll
            for (int c = 0; c < 5; ++c) S[c] += p1[c] - hist[c][7];
            if (pp >= 4) EMIT
#pragma unroll
            for (int c = 0; c < 5; ++c) {
                hist[c][8] = hist[c][6]; hist[c][7] = hist[c][5];
                hist[c][6] = hist[c][4]; hist[c][5] = hist[c][3];
                hist[c][4] = hist[c][2]; hist[c][3] = hist[c][1];
                hist[c][2] = hist[c][0];
                hist[c][1] = p0[c];
                hist[c][0] = p1[c];
            }
        }
    }
    block_reduce_atomic(local, red, &acc[0]);
}

__device__ void mse_block(const float4* __restrict__ a, const float4* __restrict__ b,
                          float* __restrict__ acc, float* red, int mb) {
    float local = 0.f;
    for (int i = mb * 256 + threadIdx.x; i < VOL / 4; i += 512 * 256) {
        const float4 x = a[i], y = b[i];
        const float d0 = x.x - y.x, d1 = x.y - y.y, d2 = x.z - y.z, d3 = x.w - y.w;
        local += d0 * d0 + d1 * d1 + d2 * d2 + d3 * d3;
    }
    block_reduce_atomic(local, red, &acc[1]);
}

__device__ void smooth_block(const float4* __restrict__ s,
                             float* __restrict__ acc, float* red, int sb) {
    float local = 0.f;
    for (int f = sb * 256 + threadIdx.x; f < FLOWN / 4; f += 2048 * 256) {
        const int w4 = f & 31, h = (f >> 5) & 127, d = (f >> 12) & 127;
        const float4 v = s[f];
        const float t1 = v.y - v.x, t2 = v.z - v.y, t3 = v.w - v.z;
        local += t1 * t1 + t2 * t2 + t3 * t3;
        if (w4 < 31) {
            const float nx = ((const float*)s)[4 * f + 4];
            const float t = nx - v.w;
            local += t * t;
        }
        if (h < 127) {
            const float4 nh = s[f + 32];
            const float u0 = nh.x - v.x, u1 = nh.y - v.y, u2 = nh.z - v.z, u3 = nh.w - v.w;
            local += u0 * u0 + u1 * u1 + u2 * u2 + u3 * u3;
        }
        if (d < 127) {
            const float4 nd = s[f + 4096];
            const float u0 = nd.x - v.x, u1 = nd.y - v.y, u2 = nd.z - v.z, u3 = nd.w - v.w;
            local += u0 * u0 + u1 * u1 + u2 * u2 + u3 * u3;
        }
    }
    block_reduce_atomic(local, red, &acc[2]);
}

// 512 ncc blocks FIRST (2/CU); mse (512) / smooth (2048) backfill the
// remaining 4 slots/CU (LDS 26.24KB -> 6 slots) and drain HBM concurrently.
__global__ __launch_bounds__(256) void fused_k(const float* __restrict__ imgsA,
                                               const float* __restrict__ recon,
                                               const float* __restrict__ warped,
                                               const float* __restrict__ flow,
                                               float* __restrict__ acc) {
    __shared__ NccLds Lsh;
    __shared__ float red[4];
    const int g = blockIdx.x;
    if (g < 512) {
        ncc_block(warped, imgsA, acc, &Lsh, red, g);
    } else {
        const int x = g - 512;
        const int q = x / 5, r = x - q * 5;
        if (r == 0) mse_block((const float4*)imgsA, (const float4*)recon, acc, red, q);
        else        smooth_block((const float4*)flow, acc, red, q * 4 + (r - 1));
    }
}

__global__ void fin_k(const float* __restrict__ acc, float* __restrict__ out) {
    if (threadIdx.x == 0) {
        out[0] = 1.0f - acc[0] * (1.0f / (float)VOL);
        out[1] = acc[1] * (1.0f / (float)VOL);
        out[2] = acc[2] * (1.0f / (3.0f * SMCNT));
    }
}

extern "C" void kernel_launch(void* const* d_in, const int* in_sizes, int n_in,
                              void* d_out, int out_size, void* d_ws, size_t ws_size,
                              hipStream_t stream) {
    const float* imgsA  = (const float*)d_in[0];
    const float* recon  = (const float*)d_in[1];
    const float* warped = (const float*)d_in[2];
    const float* flow   = (const float*)d_in[3];
    float* out = (float*)d_out;
    float* acc = (float*)d_ws;

    hipMemsetAsync(d_ws, 0, 16, stream);
    fused_k<<<3072, 256, 0, stream>>>(imgsA, recon, warped, flow, acc);
    fin_k<<<1, 64, 0, stream>>>(acc, out);
}